// Round 11
// baseline (862.994 us; speedup 1.0000x reference)
//
#include <hip/hip_runtime.h>
#include <hip/hip_bf16.h>

// ---------------------------------------------------------------------------
// GCN: 3x (GEMM -> sym-normalized aggregation(+self-loop) -> +bias -> ReLU)
//      -> global max pool per graph -> MLP head.  All fp32.
// GEMM: BM=128, BK=32, 256 thr, 8x8 micro-tile. BOTH operands staged via
//   global_load_lds (per-lane global addresses, linear LDS). A kept row-major
//   in k-quad layout Asq[kq][row][4] -> no transpose, no ds_writes in main
//   loop. K%32 tail staged manually (one iteration, b128 linear writes).
// Agg: CSR gather, float4/lane, 4-deep unroll.
// Pool: running max per block, flush on graph change (batch sorted).
// ---------------------------------------------------------------------------

typedef float f4u __attribute__((ext_vector_type(4), aligned(4)));

__global__ void deg_count_kernel(const int* __restrict__ ei, int* __restrict__ cnt, int E) {
    int e = blockIdx.x * 256 + threadIdx.x;
    if (e < E) atomicAdd(&cnt[ei[E + e]], 1);
}

__global__ void deg_fin_kernel(const int* __restrict__ cnt, float* __restrict__ disq, int N) {
    int i = blockIdx.x * 256 + threadIdx.x;
    if (i < N) disq[i] = rsqrtf((float)cnt[i] + 1.0f);
}

// ---- 2-level exclusive scan of cnt[N] -> rp[N] (chunk = 1024 = 256 thr x 4)
__global__ void scan_pass1(const int* __restrict__ cnt, int* __restrict__ bsum, int N) {
    __shared__ int s[256];
    int t = threadIdx.x;
    int base = blockIdx.x * 1024 + t * 4;
    int sum = 0;
    #pragma unroll
    for (int j = 0; j < 4; ++j) { int idx = base + j; if (idx < N) sum += cnt[idx]; }
    s[t] = sum; __syncthreads();
    for (int off = 128; off; off >>= 1) {
        if (t < off) s[t] += s[t + off];
        __syncthreads();
    }
    if (t == 0) bsum[blockIdx.x] = s[0];
}

__global__ void scan_pass2(const int* __restrict__ bsum, int* __restrict__ boff,
                           int nchunks, int* __restrict__ rp, int N, int E) {
    __shared__ int s[256];
    int t = threadIdx.x;
    int v = (t < nchunks) ? bsum[t] : 0;
    s[t] = v; __syncthreads();
    for (int off = 1; off < 256; off <<= 1) {
        int x = (t >= off) ? s[t - off] : 0;
        __syncthreads();
        s[t] += x;
        __syncthreads();
    }
    boff[t] = s[t] - v;           // exclusive
    if (t == 0) rp[N] = E;
}

__global__ void scan_pass3(const int* __restrict__ cnt, const int* __restrict__ boff,
                           int* __restrict__ rp, int N) {
    __shared__ int s[256];
    int t = threadIdx.x;
    int base = blockIdx.x * 1024 + t * 4;
    int v[4]; int sum = 0;
    #pragma unroll
    for (int j = 0; j < 4; ++j) { int idx = base + j; v[j] = (idx < N) ? cnt[idx] : 0; sum += v[j]; }
    s[t] = sum; __syncthreads();
    for (int off = 1; off < 256; off <<= 1) {
        int x = (t >= off) ? s[t - off] : 0;
        __syncthreads();
        s[t] += x;
        __syncthreads();
    }
    int ex = s[t] - sum + boff[blockIdx.x];
    #pragma unroll
    for (int j = 0; j < 4; ++j) { int idx = base + j; if (idx < N) { rp[idx] = ex; ex += v[j]; } }
}

__global__ void scatter_kernel(const int* __restrict__ ei, const float* __restrict__ disq,
                               const int* __restrict__ rp, int* __restrict__ fill,
                               int2* __restrict__ esw, int E) {
    int e = blockIdx.x * 256 + threadIdx.x;
    if (e >= E) return;
    int s = ei[e];
    int d = ei[E + e];
    int pos = rp[d] + atomicAdd(&fill[d], 1);
    int2 p; p.x = s; p.y = __float_as_int(disq[s] * disq[d]);
    esw[pos] = p;
}

// ---- fp32 GEMM: C[N,BN] = A[N,K] @ W[K,BN]
// BM=128, BK=32, 256 threads (16x16). Thread (tr,tc) owns rows
// {tr*4..+3, 64+tr*4..+3}, cols {tc*4..+3, (64+tc*4..+3 if BN==128)}.
// A staged in k-quad layout Asq[kq][128 rows][4] via glds (per-lane global
// addr, linear LDS dst). W staged linear via glds. All LDS reads b128,
// 2-way aliasing only (free).
template <int BN>
__global__ __launch_bounds__(256) void gemm_kernel(
    const float* __restrict__ A, const float* __restrict__ Wg,
    const float* __restrict__ zpad, float* __restrict__ C, int N, int K)
{
    constexpr int BM = 128, BK = 32;
    constexpr int NB = (BN == 128) ? 2 : 1;
    constexpr int WCH = (BK * BN) / 256;          // W 1KB chunks (16 or 8)
    __shared__ float Asq[8 * 128 * 4];            // [kq][row][4] = 16KB
    __shared__ float Ws[BK][BN];                  // linear (glds target)
    const int tid = threadIdx.x;
    const int tr = tid >> 4;
    const int tc = tid & 15;
    const int wv = tid >> 6;
    const int ln = tid & 63;
    const long base = (long)blockIdx.x * BM;

    float acc[8][4 * NB];
    #pragma unroll
    for (int i = 0; i < 8; ++i)
        #pragma unroll
        for (int j = 0; j < 4 * NB; ++j) acc[i][j] = 0.f;

    auto compute = [&]() {
        #pragma unroll
        for (int kq = 0; kq < 8; ++kq) {
            float4 ar[8];
            #pragma unroll
            for (int i = 0; i < 4; ++i) {
                ar[i]     = *(const float4*)&Asq[(kq * 128 + tr * 4 + i) * 4];
                ar[4 + i] = *(const float4*)&Asq[(kq * 128 + 64 + tr * 4 + i) * 4];
            }
            #pragma unroll
            for (int j = 0; j < 4; ++j) {
                int k = kq * 4 + j;
                float4 w0 = *(const float4*)&Ws[k][tc * 4];
                if constexpr (NB == 2) {
                    float4 w1 = *(const float4*)&Ws[k][64 + tc * 4];
                    float wn[8] = {w0.x, w0.y, w0.z, w0.w, w1.x, w1.y, w1.z, w1.w};
                    #pragma unroll
                    for (int i = 0; i < 8; ++i) {
                        float av = (&ar[i].x)[j];
                        #pragma unroll
                        for (int jj = 0; jj < 8; ++jj) acc[i][jj] += av * wn[jj];
                    }
                } else {
                    float wn[4] = {w0.x, w0.y, w0.z, w0.w};
                    #pragma unroll
                    for (int i = 0; i < 8; ++i) {
                        float av = (&ar[i].x)[j];
                        #pragma unroll
                        for (int jj = 0; jj < 4; ++jj) acc[i][jj] += av * wn[jj];
                    }
                }
            }
        }
    };

    const int Kmain = (K / BK) * BK;
    for (int k0 = 0; k0 < Kmain; k0 += BK) {
        // ---- stage A via glds: chunk c -> kq=c>>1, rows (c&1)*64 + ln
        #pragma unroll
        for (int c = wv; c < 16; c += 4) {
            int kq = c >> 1;
            int r  = ((c & 1) << 6) + ln;
            long row = base + r;
            const float* gp = (row < N) ? &A[row * K + k0 + kq * 4] : zpad;
            __builtin_amdgcn_global_load_lds(
                (const __attribute__((address_space(1))) void*)gp,
                (__attribute__((address_space(3))) void*)((char*)Asq + c * 1024),
                16, 0, 0);
        }
        // ---- stage W via glds
        #pragma unroll
        for (int c = wv; c < WCH; c += 4) {
            int row, coloff;
            if constexpr (BN == 128) { row = k0 + c * 2 + (ln >> 5); coloff = (ln & 31) * 4; }
            else                     { row = k0 + c * 4 + (ln >> 4); coloff = (ln & 15) * 4; }
            const float* gp = &Wg[(long)row * BN + coloff];
            char* lp = ((char*)&Ws[0][0]) + c * 1024;
            __builtin_amdgcn_global_load_lds(
                (const __attribute__((address_space(1))) void*)gp,
                (__attribute__((address_space(3))) void*)lp, 16, 0, 0);
        }
        __syncthreads();   // drains vmcnt before barrier
        compute();
        __syncthreads();
    }

    // ---- tail iteration (K % 32 != 0): manual A stage, zero-filled
    if (Kmain < K) {
        const int k0 = Kmain;
        // W via glds with clamp (A zeros annihilate clamped rows)
        #pragma unroll
        for (int c = wv; c < WCH; c += 4) {
            int row, coloff;
            if constexpr (BN == 128) { row = k0 + c * 2 + (ln >> 5); coloff = (ln & 31) * 4; }
            else                     { row = k0 + c * 4 + (ln >> 4); coloff = (ln & 15) * 4; }
            if (row > K - 1) row = K - 1;
            const float* gp = &Wg[(long)row * BN + coloff];
            char* lp = ((char*)&Ws[0][0]) + c * 1024;
            __builtin_amdgcn_global_load_lds(
                (const __attribute__((address_space(1))) void*)gp,
                (__attribute__((address_space(3))) void*)lp, 16, 0, 0);
        }
        // A manual: one ds_write_b128 per item, linear pattern
        #pragma unroll
        for (int t = 0; t < 4; ++t) {
            int i2 = tid + t * 256;               // 0..1023
            int r  = i2 & 127;
            int kq = i2 >> 7;                     // 0..7
            long row = base + r;
            float f0 = 0.f, f1 = 0.f, f2 = 0.f, f3 = 0.f;
            if (row < N) {
                const float* ap = &A[row * K + k0 + kq * 4];
                int rem = K - (k0 + kq * 4);
                if (rem >= 4) {
                    f4u v = *(const f4u*)ap;
                    f0 = v.x; f1 = v.y; f2 = v.z; f3 = v.w;
                } else {
                    if (rem > 0) f0 = ap[0];
                    if (rem > 1) f1 = ap[1];
                    if (rem > 2) f2 = ap[2];
                }
            }
            float4 v4 = {f0, f1, f2, f3};
            *(float4*)&Asq[(kq * 128 + r) * 4] = v4;
        }
        __syncthreads();
        compute();
        __syncthreads();
    }

    // ---- epilogue
    #pragma unroll
    for (int rb = 0; rb < 2; ++rb) {
        #pragma unroll
        for (int i = 0; i < 4; ++i) {
            long row = base + rb * 64 + tr * 4 + i;
            if (row < N) {
                int ai = rb * 4 + i;
                float4 v0 = {acc[ai][0], acc[ai][1], acc[ai][2], acc[ai][3]};
                *(float4*)&C[row * BN + tc * 4] = v0;
                if constexpr (NB == 2) {
                    float4 v1 = {acc[ai][4], acc[ai][5], acc[ai][6], acc[ai][7]};
                    *(float4*)&C[row * BN + 64 + tc * 4] = v1;
                }
            }
        }
    }
}

// ---- aggregation: h[i] = relu( sum_e xw[src_e]*nv_e + xw[i]*disq[i]^2 + bias )
// 4 nodes/block (one wave each). float4 per lane; EPW edges per wave-load
// (2 for C=128, 4 for C=64); 4-deep unroll.
template <int C>
__global__ __launch_bounds__(256) void agg_kernel(
    const float* __restrict__ xw, const float* __restrict__ disq,
    const int* __restrict__ rp, const int2* __restrict__ esw,
    const float* __restrict__ bias, float* __restrict__ h, int N)
{
    int i = blockIdx.x * 4 + (threadIdx.x >> 6);
    if (i >= N) return;
    int lane = threadIdx.x & 63;
    int e0 = rp[i], e1 = rp[i + 1];
    const float4* xw4 = (const float4*)xw;
    constexpr int RQ = C / 4;
    constexpr int EPW = 64 / RQ;
    int sub = lane / RQ;
    int col = lane % RQ;

    float4 a0{0,0,0,0}, a1{0,0,0,0}, a2{0,0,0,0}, a3{0,0,0,0};
    int e = e0 + sub;
    for (; e + 3 * EPW < e1; e += 4 * EPW) {
        int2 p0 = esw[e];
        int2 p1 = esw[e + EPW];
        int2 p2 = esw[e + 2 * EPW];
        int2 p3 = esw[e + 3 * EPW];
        float4 v0 = xw4[(long)p0.x * RQ + col];
        float4 v1 = xw4[(long)p1.x * RQ + col];
        float4 v2 = xw4[(long)p2.x * RQ + col];
        float4 v3 = xw4[(long)p3.x * RQ + col];
        float w0 = __int_as_float(p0.y), w1 = __int_as_float(p1.y);
        float w2 = __int_as_float(p2.y), w3 = __int_as_float(p3.y);
        a0.x += v0.x * w0; a0.y += v0.y * w0; a0.z += v0.z * w0; a0.w += v0.w * w0;
        a1.x += v1.x * w1; a1.y += v1.y * w1; a1.z += v1.z * w1; a1.w += v1.w * w1;
        a2.x += v2.x * w2; a2.y += v2.y * w2; a2.z += v2.z * w2; a2.w += v2.w * w2;
        a3.x += v3.x * w3; a3.y += v3.y * w3; a3.z += v3.z * w3; a3.w += v3.w * w3;
    }
    for (; e < e1; e += EPW) {
        int2 p0 = esw[e];
        float4 v0 = xw4[(long)p0.x * RQ + col];
        float w0 = __int_as_float(p0.y);
        a0.x += v0.x * w0; a0.y += v0.y * w0; a0.z += v0.z * w0; a0.w += v0.w * w0;
    }
    a0.x += a1.x + a2.x + a3.x;
    a0.y += a1.y + a2.y + a3.y;
    a0.z += a1.z + a2.z + a3.z;
    a0.w += a1.w + a2.w + a3.w;
    #pragma unroll
    for (int m = RQ; m < 64; m <<= 1) {
        a0.x += __shfl_xor(a0.x, m, 64);
        a0.y += __shfl_xor(a0.y, m, 64);
        a0.z += __shfl_xor(a0.z, m, 64);
        a0.w += __shfl_xor(a0.w, m, 64);
    }
    if (sub == 0) {
        float ds = disq[i];
        float ws = ds * ds;
        float4 v = xw4[(long)i * RQ + col];
        float4 b = ((const float4*)bias)[col];
        float4 o;
        o.x = fmaxf(a0.x + v.x * ws + b.x, 0.f);
        o.y = fmaxf(a0.y + v.y * ws + b.y, 0.f);
        o.z = fmaxf(a0.z + v.z * ws + b.z, 0.f);
        o.w = fmaxf(a0.w + v.w * ws + b.w, 0.f);
        ((float4*)h)[(long)i * RQ + col] = o;
    }
}

// ---- global max pool: batch sorted -> per-block running max, flush on change
__global__ __launch_bounds__(256) void pool_kernel(
    const float* __restrict__ h, const int* __restrict__ batch,
    float* __restrict__ g, int N)
{
    int c = threadIdx.x & 63;
    int slot = threadIdx.x >> 6;
    int base = blockIdx.x * 512;
    int end = base + 512; if (end > N) end = N;
    int cur = -1; float m = 0.f;
    for (int n = base + slot; n < end; n += 4) {
        int b = batch[n];
        float v = h[(long)n * 64 + c];
        if (b != cur) {
            if (cur >= 0) atomicMax((int*)&g[cur * 64 + c], __float_as_int(m));
            cur = b; m = v;
        } else {
            m = fmaxf(m, v);
        }
    }
    if (cur >= 0) atomicMax((int*)&g[cur * 64 + c], __float_as_int(m));
}

// ---- head: out[r] = relu(g[r]@Wh1+bh1) @ Wh2 + bh2
__global__ void head_kernel(const float* __restrict__ g, const float* __restrict__ Wh1,
                            const float* __restrict__ bh1, const float* __restrict__ Wh2,
                            const float* __restrict__ bh2, float* __restrict__ out, int G) {
    int r = threadIdx.x;
    if (r >= G) return;
    float hid[32];
    #pragma unroll
    for (int j = 0; j < 32; ++j) {
        float s = bh1[j];
        for (int k = 0; k < 64; ++k) s += g[r * 64 + k] * Wh1[k * 32 + j];
        hid[j] = fmaxf(s, 0.f);
    }
    float o = bh2[0];
    #pragma unroll
    for (int j = 0; j < 32; ++j) o += hid[j] * Wh2[j];
    out[r] = o;
}

extern "C" void kernel_launch(void* const* d_in, const int* in_sizes, int n_in,
                              void* d_out, int out_size, void* d_ws, size_t ws_size,
                              hipStream_t stream) {
    const float* x   = (const float*)d_in[0];
    const int*   ei  = (const int*)d_in[1];
    const int*   bat = (const int*)d_in[2];
    const float* W1  = (const float*)d_in[3];
    const float* b1  = (const float*)d_in[4];
    const float* W2  = (const float*)d_in[5];
    const float* b2  = (const float*)d_in[6];
    const float* W3  = (const float*)d_in[7];
    const float* b3  = (const float*)d_in[8];
    const float* Wh1 = (const float*)d_in[9];
    const float* bh1 = (const float*)d_in[10];
    const float* Wh2 = (const float*)d_in[11];
    const float* bh2 = (const float*)d_in[12];
    float* out = (float*)d_out;

    const int N = in_sizes[2];
    const int E = in_sizes[1] / 2;
    const int K1 = in_sizes[0] / N;   // 397
    const int G = out_size;           // 64

    char* wsp = (char*)d_ws;
    size_t off = 0;
    auto alloc = [&](size_t bytes) -> void* {
        void* p = wsp + off;
        off = (off + bytes + 255) & ~(size_t)255;
        return p;
    };
    int*   cnt  = (int*)alloc((size_t)N * 4);
    float* disq = (float*)alloc((size_t)N * 4);
    int*   rp   = (int*)alloc((size_t)(N + 1) * 4);
    int*   bsum = (int*)alloc(256 * 4);
    int*   boff = (int*)alloc(256 * 4);
    float* zpad = (float*)alloc(256);
    int2*  esw  = (int2*)alloc((size_t)E * 8);
    float* B0   = (float*)alloc((size_t)N * 128 * 4);
    float* B1   = (float*)alloc((size_t)N * 128 * 4);
    float* g    = (float*)alloc((size_t)G * 64 * 4);

    const int nchunks = (N + 1023) / 1024;

    (void)hipMemsetAsync(cnt, 0, (size_t)N * 4, stream);
    (void)hipMemsetAsync(zpad, 0, 256, stream);
    deg_count_kernel<<<(E + 255) / 256, 256, 0, stream>>>(ei, cnt, E);
    deg_fin_kernel<<<(N + 255) / 256, 256, 0, stream>>>(cnt, disq, N);
    scan_pass1<<<nchunks, 256, 0, stream>>>(cnt, bsum, N);
    scan_pass2<<<1, 256, 0, stream>>>(bsum, boff, nchunks, rp, N, E);
    scan_pass3<<<nchunks, 256, 0, stream>>>(cnt, boff, rp, N);
    (void)hipMemsetAsync(cnt, 0, (size_t)N * 4, stream);
    scatter_kernel<<<(E + 255) / 256, 256, 0, stream>>>(ei, disq, rp, cnt, esw, E);

    int gblocks = (N + 127) / 128;
    int ablocks = (N + 3) / 4;
    // layer 1
    gemm_kernel<128><<<gblocks, 256, 0, stream>>>(x, W1, zpad, B0, N, K1);
    agg_kernel<128><<<ablocks, 256, 0, stream>>>(B0, disq, rp, esw, b1, B1, N);
    // layer 2
    gemm_kernel<128><<<gblocks, 256, 0, stream>>>(B1, W2, zpad, B0, N, 128);
    agg_kernel<128><<<ablocks, 256, 0, stream>>>(B0, disq, rp, esw, b2, B1, N);
    // layer 3
    gemm_kernel<64><<<gblocks, 256, 0, stream>>>(B1, W3, zpad, B0, N, 128);
    agg_kernel<64><<<ablocks, 256, 0, stream>>>(B0, disq, rp, esw, b3, B1, N);
    // pool + head
    (void)hipMemsetAsync(g, 0, (size_t)G * 64 * 4, stream);
    pool_kernel<<<(N + 511) / 512, 256, 0, stream>>>(B1, bat, g, N);
    head_kernel<<<1, 64, 0, stream>>>(g, Wh1, bh1, Wh2, bh2, out, G);
}

// Round 12
// 680.440 us; speedup vs baseline: 1.2683x; 1.2683x over previous
//
#include <hip/hip_runtime.h>
#include <hip/hip_bf16.h>

// ---------------------------------------------------------------------------
// GCN: 3x (GEMM -> sym-normalized aggregation(+self-loop) -> +bias -> ReLU)
//      -> global max pool per graph -> MLP head.
// GEMM via MFMA bf16 hi/lo split (3 products, ~16-bit mantissa):
//   mfma_f32_16x16x32_bf16, BM=128, 4 waves x (32 rows x BN cols).
//   Layer 1 converts fp32->hi/lo during LDS staging; agg writes next layer's
//   input as bf16 hi/lo directly. Everything else fp32 (round-10 structure).
// ---------------------------------------------------------------------------

typedef float f4u __attribute__((ext_vector_type(4), aligned(4)));
typedef unsigned short u16;
typedef u16 u16x8 __attribute__((ext_vector_type(8)));
typedef u16 u16x4 __attribute__((ext_vector_type(4)));
typedef short bf16x8 __attribute__((ext_vector_type(8)));
typedef float f32x4 __attribute__((ext_vector_type(4)));

__device__ __forceinline__ u16 bf16_rne(float f) {
    unsigned u = __float_as_uint(f);
    return (u16)((u + 0x7FFF + ((u >> 16) & 1)) >> 16);
}
__device__ __forceinline__ float bf16_f(u16 h) {
    return __uint_as_float(((unsigned)h) << 16);
}

__global__ void deg_count_kernel(const int* __restrict__ ei, int* __restrict__ cnt, int E) {
    int e = blockIdx.x * 256 + threadIdx.x;
    if (e < E) atomicAdd(&cnt[ei[E + e]], 1);
}

__global__ void deg_fin_kernel(const int* __restrict__ cnt, float* __restrict__ disq, int N) {
    int i = blockIdx.x * 256 + threadIdx.x;
    if (i < N) disq[i] = rsqrtf((float)cnt[i] + 1.0f);
}

__global__ void scan_pass1(const int* __restrict__ cnt, int* __restrict__ bsum, int N) {
    __shared__ int s[256];
    int t = threadIdx.x;
    int base = blockIdx.x * 1024 + t * 4;
    int sum = 0;
    #pragma unroll
    for (int j = 0; j < 4; ++j) { int idx = base + j; if (idx < N) sum += cnt[idx]; }
    s[t] = sum; __syncthreads();
    for (int off = 128; off; off >>= 1) {
        if (t < off) s[t] += s[t + off];
        __syncthreads();
    }
    if (t == 0) bsum[blockIdx.x] = s[0];
}

__global__ void scan_pass2(const int* __restrict__ bsum, int* __restrict__ boff,
                           int nchunks, int* __restrict__ rp, int N, int E) {
    __shared__ int s[256];
    int t = threadIdx.x;
    int v = (t < nchunks) ? bsum[t] : 0;
    s[t] = v; __syncthreads();
    for (int off = 1; off < 256; off <<= 1) {
        int x = (t >= off) ? s[t - off] : 0;
        __syncthreads();
        s[t] += x;
        __syncthreads();
    }
    boff[t] = s[t] - v;
    if (t == 0) rp[N] = E;
}

__global__ void scan_pass3(const int* __restrict__ cnt, const int* __restrict__ boff,
                           int* __restrict__ rp, int N) {
    __shared__ int s[256];
    int t = threadIdx.x;
    int base = blockIdx.x * 1024 + t * 4;
    int v[4]; int sum = 0;
    #pragma unroll
    for (int j = 0; j < 4; ++j) { int idx = base + j; v[j] = (idx < N) ? cnt[idx] : 0; sum += v[j]; }
    s[t] = sum; __syncthreads();
    for (int off = 1; off < 256; off <<= 1) {
        int x = (t >= off) ? s[t - off] : 0;
        __syncthreads();
        s[t] += x;
        __syncthreads();
    }
    int ex = s[t] - sum + boff[blockIdx.x];
    #pragma unroll
    for (int j = 0; j < 4; ++j) { int idx = base + j; if (idx < N) { rp[idx] = ex; ex += v[j]; } }
}

__global__ void scatter_kernel(const int* __restrict__ ei, const float* __restrict__ disq,
                               const int* __restrict__ rp, int* __restrict__ fill,
                               int2* __restrict__ esw, int E) {
    int e = blockIdx.x * 256 + threadIdx.x;
    if (e >= E) return;
    int s = ei[e];
    int d = ei[E + e];
    int pos = rp[d] + atomicAdd(&fill[d], 1);
    int2 p; p.x = s; p.y = __float_as_int(disq[s] * disq[d]);
    esw[pos] = p;
}

// ---- W convert+transpose: Wt[c][k] = hi/lo(W[k][c]), k zero-padded to KP
__global__ void cvtw_kernel(const float* __restrict__ W, u16* __restrict__ Wthi,
                            u16* __restrict__ Wtlo, int K, int KP, int BN) {
    int idx = blockIdx.x * 256 + threadIdx.x;
    if (idx >= KP * BN) return;
    int c = idx / KP;
    int k = idx % KP;
    float v = (k < K) ? W[(long)k * BN + c] : 0.f;
    u16 h = bf16_rne(v);
    Wthi[idx] = h;
    Wtlo[idx] = bf16_rne(v - bf16_f(h));
}

// ---- MFMA GEMM: C[N,BN] fp32 = A[N,K] @ W[K,BN] via bf16 hi/lo split.
// BM=128, BK=32, 256 thr (4 waves). Wave w: rows w*32..+31 (2 frag-rows),
// cols 0..BN (FC frag-cols). 3 mfma per tile (hh, lh, hl).
// A: AFP32 ? fp32 source converted during staging : bf16 hi/lo source.
// W: pre-converted transposed Wt[c][kp].  LDS rows padded to 40 bf16.
template <int BN, bool AFP32>
__global__ __launch_bounds__(256) void mfma_gemm(
    const float* __restrict__ Af, const u16* __restrict__ Ahi,
    const u16* __restrict__ Alo, const u16* __restrict__ Wthi,
    const u16* __restrict__ Wtlo, float* __restrict__ C, int N, int K, int KP)
{
    constexpr int FC = BN / 16;
    __shared__ u16 Ah[128 * 40];
    __shared__ u16 Al[128 * 40];
    __shared__ u16 Wh[BN * 40];
    __shared__ u16 Wl[BN * 40];
    const int tid = threadIdx.x;
    const int w = tid >> 6;
    const int l = tid & 63;
    const int l15 = l & 15;
    const int koff = (l >> 4) * 8;
    const long base = (long)blockIdx.x * 128;

    f32x4 acc[2][FC];
    #pragma unroll
    for (int i = 0; i < 2; ++i)
        #pragma unroll
        for (int j = 0; j < FC; ++j) acc[i][j] = (f32x4){0.f, 0.f, 0.f, 0.f};

    for (int k0 = 0; k0 < KP; k0 += 32) {
        // ---- stage A (hi/lo) : 512 chunks of 8 k-elems
        #pragma unroll
        for (int it = 0; it < 2; ++it) {
            int i2 = tid + it * 256;
            int r = i2 >> 2;
            int kq = (i2 & 3) * 8;
            long row = base + r;
            u16x8 hv = (u16x8)0, lv = (u16x8)0;
            if constexpr (AFP32) {
                int rem = K - (k0 + kq);
                if (row < N && rem > 0) {
                    const float* ap = &Af[row * (long)K + k0 + kq];
                    float f[8];
                    if (rem >= 8) {
                        f4u v0 = *(const f4u*)ap;
                        f4u v1 = *(const f4u*)(ap + 4);
                        f[0] = v0.x; f[1] = v0.y; f[2] = v0.z; f[3] = v0.w;
                        f[4] = v1.x; f[5] = v1.y; f[6] = v1.z; f[7] = v1.w;
                    } else {
                        #pragma unroll
                        for (int j = 0; j < 8; ++j) f[j] = (j < rem) ? ap[j] : 0.f;
                    }
                    #pragma unroll
                    for (int j = 0; j < 8; ++j) {
                        u16 h = bf16_rne(f[j]);
                        hv[j] = h;
                        lv[j] = bf16_rne(f[j] - bf16_f(h));
                    }
                }
            } else {
                if (row < N) {
                    hv = *(const u16x8*)&Ahi[row * (long)K + k0 + kq];
                    lv = *(const u16x8*)&Alo[row * (long)K + k0 + kq];
                }
            }
            *(u16x8*)&Ah[r * 40 + kq] = hv;
            *(u16x8*)&Al[r * 40 + kq] = lv;
        }
        // ---- stage W (hi/lo): BN*4 chunks
        #pragma unroll
        for (int it = 0; it < (BN * 4) / 256; ++it) {
            int i2 = tid + it * 256;
            int c = i2 >> 2;
            int kq = (i2 & 3) * 8;
            *(u16x8*)&Wh[c * 40 + kq] = *(const u16x8*)&Wthi[(long)c * KP + k0 + kq];
            *(u16x8*)&Wl[c * 40 + kq] = *(const u16x8*)&Wtlo[(long)c * KP + k0 + kq];
        }
        __syncthreads();
        // ---- fragments + MFMA
        bf16x8 ah[2], al[2];
        #pragma unroll
        for (int fr = 0; fr < 2; ++fr) {
            int ar = (w * 32 + fr * 16 + l15) * 40 + koff;
            ah[fr] = *(const bf16x8*)&Ah[ar];
            al[fr] = *(const bf16x8*)&Al[ar];
        }
        #pragma unroll
        for (int fc = 0; fc < FC; ++fc) {
            int wr = (fc * 16 + l15) * 40 + koff;
            bf16x8 bh = *(const bf16x8*)&Wh[wr];
            bf16x8 bl = *(const bf16x8*)&Wl[wr];
            #pragma unroll
            for (int fr = 0; fr < 2; ++fr) {
                acc[fr][fc] = __builtin_amdgcn_mfma_f32_16x16x32_bf16(ah[fr], bh, acc[fr][fc], 0, 0, 0);
                acc[fr][fc] = __builtin_amdgcn_mfma_f32_16x16x32_bf16(al[fr], bh, acc[fr][fc], 0, 0, 0);
                acc[fr][fc] = __builtin_amdgcn_mfma_f32_16x16x32_bf16(ah[fr], bl, acc[fr][fc], 0, 0, 0);
            }
        }
        __syncthreads();
    }
    // ---- epilogue: D col=lane&15, row=(lane>>4)*4+reg
    #pragma unroll
    for (int fr = 0; fr < 2; ++fr) {
        #pragma unroll
        for (int fc = 0; fc < FC; ++fc) {
            int col = fc * 16 + l15;
            #pragma unroll
            for (int reg = 0; reg < 4; ++reg) {
                long row = base + w * 32 + fr * 16 + (l >> 4) * 4 + reg;
                if (row < N) C[row * BN + col] = acc[fr][fc][reg];
            }
        }
    }
}

// ---- aggregation: h[i] = relu( sum_e xw[src_e]*nv_e + xw[i]*disq[i]^2 + bias )
// B16OUT: write result as bf16 hi/lo (input for next MFMA GEMM).
template <int C, bool B16OUT>
__global__ __launch_bounds__(256) void agg_kernel(
    const float* __restrict__ xw, const float* __restrict__ disq,
    const int* __restrict__ rp, const int2* __restrict__ esw,
    const float* __restrict__ bias, float* __restrict__ h,
    u16* __restrict__ hhi, u16* __restrict__ hlo, int N)
{
    int i = blockIdx.x * 4 + (threadIdx.x >> 6);
    if (i >= N) return;
    int lane = threadIdx.x & 63;
    int e0 = rp[i], e1 = rp[i + 1];
    const float4* xw4 = (const float4*)xw;
    constexpr int RQ = C / 4;
    constexpr int EPW = 64 / RQ;
    int sub = lane / RQ;
    int col = lane % RQ;

    float4 a0{0,0,0,0}, a1{0,0,0,0}, a2{0,0,0,0}, a3{0,0,0,0};
    int e = e0 + sub;
    for (; e + 3 * EPW < e1; e += 4 * EPW) {
        int2 p0 = esw[e];
        int2 p1 = esw[e + EPW];
        int2 p2 = esw[e + 2 * EPW];
        int2 p3 = esw[e + 3 * EPW];
        float4 v0 = xw4[(long)p0.x * RQ + col];
        float4 v1 = xw4[(long)p1.x * RQ + col];
        float4 v2 = xw4[(long)p2.x * RQ + col];
        float4 v3 = xw4[(long)p3.x * RQ + col];
        float w0 = __int_as_float(p0.y), w1 = __int_as_float(p1.y);
        float w2 = __int_as_float(p2.y), w3 = __int_as_float(p3.y);
        a0.x += v0.x * w0; a0.y += v0.y * w0; a0.z += v0.z * w0; a0.w += v0.w * w0;
        a1.x += v1.x * w1; a1.y += v1.y * w1; a1.z += v1.z * w1; a1.w += v1.w * w1;
        a2.x += v2.x * w2; a2.y += v2.y * w2; a2.z += v2.z * w2; a2.w += v2.w * w2;
        a3.x += v3.x * w3; a3.y += v3.y * w3; a3.z += v3.z * w3; a3.w += v3.w * w3;
    }
    for (; e < e1; e += EPW) {
        int2 p0 = esw[e];
        float4 v0 = xw4[(long)p0.x * RQ + col];
        float w0 = __int_as_float(p0.y);
        a0.x += v0.x * w0; a0.y += v0.y * w0; a0.z += v0.z * w0; a0.w += v0.w * w0;
    }
    a0.x += a1.x + a2.x + a3.x;
    a0.y += a1.y + a2.y + a3.y;
    a0.z += a1.z + a2.z + a3.z;
    a0.w += a1.w + a2.w + a3.w;
    #pragma unroll
    for (int m = RQ; m < 64; m <<= 1) {
        a0.x += __shfl_xor(a0.x, m, 64);
        a0.y += __shfl_xor(a0.y, m, 64);
        a0.z += __shfl_xor(a0.z, m, 64);
        a0.w += __shfl_xor(a0.w, m, 64);
    }
    if (sub == 0) {
        float ds = disq[i];
        float ws = ds * ds;
        float4 v = xw4[(long)i * RQ + col];
        float4 b = ((const float4*)bias)[col];
        float o[4];
        o[0] = fmaxf(a0.x + v.x * ws + b.x, 0.f);
        o[1] = fmaxf(a0.y + v.y * ws + b.y, 0.f);
        o[2] = fmaxf(a0.z + v.z * ws + b.z, 0.f);
        o[3] = fmaxf(a0.w + v.w * ws + b.w, 0.f);
        if constexpr (B16OUT) {
            u16x4 oh, ol;
            #pragma unroll
            for (int j = 0; j < 4; ++j) {
                u16 hh = bf16_rne(o[j]);
                oh[j] = hh;
                ol[j] = bf16_rne(o[j] - bf16_f(hh));
            }
            *(u16x4*)&hhi[(long)i * C + col * 4] = oh;
            *(u16x4*)&hlo[(long)i * C + col * 4] = ol;
        } else {
            float4 ov = {o[0], o[1], o[2], o[3]};
            ((float4*)h)[(long)i * RQ + col] = ov;
        }
    }
}

// ---- global max pool: batch sorted -> per-block running max, flush on change
__global__ __launch_bounds__(256) void pool_kernel(
    const float* __restrict__ h, const int* __restrict__ batch,
    float* __restrict__ g, int N)
{
    int c = threadIdx.x & 63;
    int slot = threadIdx.x >> 6;
    int base = blockIdx.x * 512;
    int end = base + 512; if (end > N) end = N;
    int cur = -1; float m = 0.f;
    for (int n = base + slot; n < end; n += 4) {
        int b = batch[n];
        float v = h[(long)n * 64 + c];
        if (b != cur) {
            if (cur >= 0) atomicMax((int*)&g[cur * 64 + c], __float_as_int(m));
            cur = b; m = v;
        } else {
            m = fmaxf(m, v);
        }
    }
    if (cur >= 0) atomicMax((int*)&g[cur * 64 + c], __float_as_int(m));
}

// ---- head: out[r] = relu(g[r]@Wh1+bh1) @ Wh2 + bh2
__global__ void head_kernel(const float* __restrict__ g, const float* __restrict__ Wh1,
                            const float* __restrict__ bh1, const float* __restrict__ Wh2,
                            const float* __restrict__ bh2, float* __restrict__ out, int G) {
    int r = threadIdx.x;
    if (r >= G) return;
    float hid[32];
    #pragma unroll
    for (int j = 0; j < 32; ++j) {
        float s = bh1[j];
        for (int k = 0; k < 64; ++k) s += g[r * 64 + k] * Wh1[k * 32 + j];
        hid[j] = fmaxf(s, 0.f);
    }
    float o = bh2[0];
    #pragma unroll
    for (int j = 0; j < 32; ++j) o += hid[j] * Wh2[j];
    out[r] = o;
}

extern "C" void kernel_launch(void* const* d_in, const int* in_sizes, int n_in,
                              void* d_out, int out_size, void* d_ws, size_t ws_size,
                              hipStream_t stream) {
    const float* x   = (const float*)d_in[0];
    const int*   ei  = (const int*)d_in[1];
    const int*   bat = (const int*)d_in[2];
    const float* W1  = (const float*)d_in[3];
    const float* b1  = (const float*)d_in[4];
    const float* W2  = (const float*)d_in[5];
    const float* b2  = (const float*)d_in[6];
    const float* W3  = (const float*)d_in[7];
    const float* b3  = (const float*)d_in[8];
    const float* Wh1 = (const float*)d_in[9];
    const float* bh1 = (const float*)d_in[10];
    const float* Wh2 = (const float*)d_in[11];
    const float* bh2 = (const float*)d_in[12];
    float* out = (float*)d_out;

    const int N = in_sizes[2];
    const int E = in_sizes[1] / 2;
    const int K1 = in_sizes[0] / N;          // 397
    const int G = out_size;                  // 64
    const int KP1 = ((K1 + 31) / 32) * 32;   // 416

    char* wsp = (char*)d_ws;
    size_t off = 0;
    auto alloc = [&](size_t bytes) -> void* {
        void* p = wsp + off;
        off = (off + bytes + 255) & ~(size_t)255;
        return p;
    };
    int*   cnt   = (int*)alloc((size_t)N * 4);
    float* disq  = (float*)alloc((size_t)N * 4);
    int*   rp    = (int*)alloc((size_t)(N + 1) * 4);
    int*   bsum  = (int*)alloc(256 * 4);
    int*   boff  = (int*)alloc(256 * 4);
    int2*  esw   = (int2*)alloc((size_t)E * 8);
    u16*   Wt1hi = (u16*)alloc((size_t)KP1 * 128 * 2);
    u16*   Wt1lo = (u16*)alloc((size_t)KP1 * 128 * 2);
    u16*   Wt2hi = (u16*)alloc((size_t)128 * 128 * 2);
    u16*   Wt2lo = (u16*)alloc((size_t)128 * 128 * 2);
    u16*   Wt3hi = (u16*)alloc((size_t)128 * 64 * 2);
    u16*   Wt3lo = (u16*)alloc((size_t)128 * 64 * 2);
    float* B0    = (float*)alloc((size_t)N * 128 * 4);   // GEMM out (fp32)
    u16*   Hhi   = (u16*)alloc((size_t)N * 128 * 2);     // agg out hi
    u16*   Hlo   = (u16*)alloc((size_t)N * 128 * 2);     // agg out lo
    float* h3    = (float*)alloc((size_t)N * 64 * 4);    // layer-3 agg out
    float* g     = (float*)alloc((size_t)G * 64 * 4);

    const int nchunks = (N + 1023) / 1024;

    (void)hipMemsetAsync(cnt, 0, (size_t)N * 4, stream);
    deg_count_kernel<<<(E + 255) / 256, 256, 0, stream>>>(ei, cnt, E);
    deg_fin_kernel<<<(N + 255) / 256, 256, 0, stream>>>(cnt, disq, N);
    scan_pass1<<<nchunks, 256, 0, stream>>>(cnt, bsum, N);
    scan_pass2<<<1, 256, 0, stream>>>(bsum, boff, nchunks, rp, N, E);
    scan_pass3<<<nchunks, 256, 0, stream>>>(cnt, boff, rp, N);
    (void)hipMemsetAsync(cnt, 0, (size_t)N * 4, stream);
    scatter_kernel<<<(E + 255) / 256, 256, 0, stream>>>(ei, disq, rp, cnt, esw, E);

    // weight conversions (tiny)
    cvtw_kernel<<<(KP1 * 128 + 255) / 256, 256, 0, stream>>>(W1, Wt1hi, Wt1lo, K1, KP1, 128);
    cvtw_kernel<<<(128 * 128 + 255) / 256, 256, 0, stream>>>(W2, Wt2hi, Wt2lo, 128, 128, 128);
    cvtw_kernel<<<(128 * 64 + 255) / 256, 256, 0, stream>>>(W3, Wt3hi, Wt3lo, 128, 128, 64);

    int gblocks = (N + 127) / 128;
    int ablocks = (N + 3) / 4;
    // layer 1
    mfma_gemm<128, true><<<gblocks, 256, 0, stream>>>(x, nullptr, nullptr, Wt1hi, Wt1lo, B0, N, K1, KP1);
    agg_kernel<128, true><<<ablocks, 256, 0, stream>>>(B0, disq, rp, esw, b1, nullptr, Hhi, Hlo, N);
    // layer 2
    mfma_gemm<128, false><<<gblocks, 256, 0, stream>>>(nullptr, Hhi, Hlo, Wt2hi, Wt2lo, B0, N, 128, 128);
    agg_kernel<128, true><<<ablocks, 256, 0, stream>>>(B0, disq, rp, esw, b2, nullptr, Hhi, Hlo, N);
    // layer 3
    mfma_gemm<64, false><<<gblocks, 256, 0, stream>>>(nullptr, Hhi, Hlo, Wt3hi, Wt3lo, B0, N, 128, 128);
    agg_kernel<64, false><<<ablocks, 256, 0, stream>>>(B0, disq, rp, esw, b3, h3, nullptr, nullptr, N);
    // pool + head
    (void)hipMemsetAsync(g, 0, (size_t)G * 64 * 4, stream);
    pool_kernel<<<(N + 511) / 512, 256, 0, stream>>>(h3, bat, g, N);
    head_kernel<<<1, 64, 0, stream>>>(g, Wh1, bh1, Wh2, bh2, out, G);
}

// Round 13
// 547.109 us; speedup vs baseline: 1.5774x; 1.2437x over previous
//
#include <hip/hip_runtime.h>
#include <hip/hip_bf16.h>
#include <hip/hip_fp16.h>

// ---------------------------------------------------------------------------
// GCN: 3x (GEMM -> sym-normalized aggregation(+self-loop) -> +bias -> ReLU)
//      -> global max pool per graph -> MLP head.
// GEMM via MFMA bf16 hi/lo split (3 products, ~16-bit mantissa); GEMM output
//   written once as an fp16 plane (gather format). Agg gathers fp16 (half the
//   bytes), accumulates fp32, emits bf16 hi/lo for the next GEMM.
// ---------------------------------------------------------------------------

typedef float f4u __attribute__((ext_vector_type(4), aligned(4)));
typedef unsigned short u16;
typedef u16 u16x8 __attribute__((ext_vector_type(8)));
typedef short bf16x8 __attribute__((ext_vector_type(8)));
typedef float f32x4 __attribute__((ext_vector_type(4)));
typedef _Float16 f16;
typedef f16 f16x8 __attribute__((ext_vector_type(8)));

__device__ __forceinline__ u16 bf16_rne(float f) {
    unsigned u = __float_as_uint(f);
    return (u16)((u + 0x7FFF + ((u >> 16) & 1)) >> 16);
}
__device__ __forceinline__ float bf16_f(u16 h) {
    return __uint_as_float(((unsigned)h) << 16);
}

__global__ void deg_count_kernel(const int* __restrict__ ei, int* __restrict__ cnt, int E) {
    int e = blockIdx.x * 256 + threadIdx.x;
    if (e < E) atomicAdd(&cnt[ei[E + e]], 1);
}

__global__ void deg_fin_kernel(const int* __restrict__ cnt, float* __restrict__ disq, int N) {
    int i = blockIdx.x * 256 + threadIdx.x;
    if (i < N) disq[i] = rsqrtf((float)cnt[i] + 1.0f);
}

__global__ void scan_pass1(const int* __restrict__ cnt, int* __restrict__ bsum, int N) {
    __shared__ int s[256];
    int t = threadIdx.x;
    int base = blockIdx.x * 1024 + t * 4;
    int sum = 0;
    #pragma unroll
    for (int j = 0; j < 4; ++j) { int idx = base + j; if (idx < N) sum += cnt[idx]; }
    s[t] = sum; __syncthreads();
    for (int off = 128; off; off >>= 1) {
        if (t < off) s[t] += s[t + off];
        __syncthreads();
    }
    if (t == 0) bsum[blockIdx.x] = s[0];
}

__global__ void scan_pass2(const int* __restrict__ bsum, int* __restrict__ boff,
                           int nchunks, int* __restrict__ rp, int N, int E) {
    __shared__ int s[256];
    int t = threadIdx.x;
    int v = (t < nchunks) ? bsum[t] : 0;
    s[t] = v; __syncthreads();
    for (int off = 1; off < 256; off <<= 1) {
        int x = (t >= off) ? s[t - off] : 0;
        __syncthreads();
        s[t] += x;
        __syncthreads();
    }
    boff[t] = s[t] - v;
    if (t == 0) rp[N] = E;
}

__global__ void scan_pass3(const int* __restrict__ cnt, const int* __restrict__ boff,
                           int* __restrict__ rp, int N) {
    __shared__ int s[256];
    int t = threadIdx.x;
    int base = blockIdx.x * 1024 + t * 4;
    int v[4]; int sum = 0;
    #pragma unroll
    for (int j = 0; j < 4; ++j) { int idx = base + j; v[j] = (idx < N) ? cnt[idx] : 0; sum += v[j]; }
    s[t] = sum; __syncthreads();
    for (int off = 1; off < 256; off <<= 1) {
        int x = (t >= off) ? s[t - off] : 0;
        __syncthreads();
        s[t] += x;
        __syncthreads();
    }
    int ex = s[t] - sum + boff[blockIdx.x];
    #pragma unroll
    for (int j = 0; j < 4; ++j) { int idx = base + j; if (idx < N) { rp[idx] = ex; ex += v[j]; } }
}

__global__ void scatter_kernel(const int* __restrict__ ei, const float* __restrict__ disq,
                               const int* __restrict__ rp, int* __restrict__ fill,
                               int2* __restrict__ esw, int E) {
    int e = blockIdx.x * 256 + threadIdx.x;
    if (e >= E) return;
    int s = ei[e];
    int d = ei[E + e];
    int pos = rp[d] + atomicAdd(&fill[d], 1);
    int2 p; p.x = s; p.y = __float_as_int(disq[s] * disq[d]);
    esw[pos] = p;
}

// ---- W convert+transpose: Wt[c][k] = hi/lo(W[k][c]), k zero-padded to KP
__global__ void cvtw_kernel(const float* __restrict__ W, u16* __restrict__ Wthi,
                            u16* __restrict__ Wtlo, int K, int KP, int BN) {
    int idx = blockIdx.x * 256 + threadIdx.x;
    if (idx >= KP * BN) return;
    int c = idx / KP;
    int k = idx % KP;
    float v = (k < K) ? W[(long)k * BN + c] : 0.f;
    u16 h = bf16_rne(v);
    Wthi[idx] = h;
    Wtlo[idx] = bf16_rne(v - bf16_f(h));
}

// ---- MFMA GEMM: Xh[N,BN] fp16 = A[N,K] @ W[K,BN] via bf16 hi/lo split.
// BM=128, BK=32, 256 thr (4 waves). Wave w: rows w*32..+31 (2 frag-rows).
template <int BN, bool AFP32>
__global__ __launch_bounds__(256) void mfma_gemm(
    const float* __restrict__ Af, const u16* __restrict__ Ahi,
    const u16* __restrict__ Alo, const u16* __restrict__ Wthi,
    const u16* __restrict__ Wtlo, f16* __restrict__ Xh, int N, int K, int KP)
{
    constexpr int FC = BN / 16;
    __shared__ u16 Ah[128 * 40];
    __shared__ u16 Al[128 * 40];
    __shared__ u16 Wh[BN * 40];
    __shared__ u16 Wl[BN * 40];
    const int tid = threadIdx.x;
    const int w = tid >> 6;
    const int l = tid & 63;
    const int l15 = l & 15;
    const int koff = (l >> 4) * 8;
    const long base = (long)blockIdx.x * 128;

    f32x4 acc[2][FC];
    #pragma unroll
    for (int i = 0; i < 2; ++i)
        #pragma unroll
        for (int j = 0; j < FC; ++j) acc[i][j] = (f32x4){0.f, 0.f, 0.f, 0.f};

    for (int k0 = 0; k0 < KP; k0 += 32) {
        #pragma unroll
        for (int it = 0; it < 2; ++it) {
            int i2 = tid + it * 256;
            int r = i2 >> 2;
            int kq = (i2 & 3) * 8;
            long row = base + r;
            u16x8 hv = (u16x8)0, lv = (u16x8)0;
            if constexpr (AFP32) {
                int rem = K - (k0 + kq);
                if (row < N && rem > 0) {
                    const float* ap = &Af[row * (long)K + k0 + kq];
                    float f[8];
                    if (rem >= 8) {
                        f4u v0 = *(const f4u*)ap;
                        f4u v1 = *(const f4u*)(ap + 4);
                        f[0] = v0.x; f[1] = v0.y; f[2] = v0.z; f[3] = v0.w;
                        f[4] = v1.x; f[5] = v1.y; f[6] = v1.z; f[7] = v1.w;
                    } else {
                        #pragma unroll
                        for (int j = 0; j < 8; ++j) f[j] = (j < rem) ? ap[j] : 0.f;
                    }
                    #pragma unroll
                    for (int j = 0; j < 8; ++j) {
                        u16 h = bf16_rne(f[j]);
                        hv[j] = h;
                        lv[j] = bf16_rne(f[j] - bf16_f(h));
                    }
                }
            } else {
                if (row < N) {
                    hv = *(const u16x8*)&Ahi[row * (long)K + k0 + kq];
                    lv = *(const u16x8*)&Alo[row * (long)K + k0 + kq];
                }
            }
            *(u16x8*)&Ah[r * 40 + kq] = hv;
            *(u16x8*)&Al[r * 40 + kq] = lv;
        }
        #pragma unroll
        for (int it = 0; it < (BN * 4) / 256; ++it) {
            int i2 = tid + it * 256;
            int c = i2 >> 2;
            int kq = (i2 & 3) * 8;
            *(u16x8*)&Wh[c * 40 + kq] = *(const u16x8*)&Wthi[(long)c * KP + k0 + kq];
            *(u16x8*)&Wl[c * 40 + kq] = *(const u16x8*)&Wtlo[(long)c * KP + k0 + kq];
        }
        __syncthreads();
        bf16x8 ah[2], al[2];
        #pragma unroll
        for (int fr = 0; fr < 2; ++fr) {
            int ar = (w * 32 + fr * 16 + l15) * 40 + koff;
            ah[fr] = *(const bf16x8*)&Ah[ar];
            al[fr] = *(const bf16x8*)&Al[ar];
        }
        #pragma unroll
        for (int fc = 0; fc < FC; ++fc) {
            int wr = (fc * 16 + l15) * 40 + koff;
            bf16x8 bh = *(const bf16x8*)&Wh[wr];
            bf16x8 bl = *(const bf16x8*)&Wl[wr];
            #pragma unroll
            for (int fr = 0; fr < 2; ++fr) {
                acc[fr][fc] = __builtin_amdgcn_mfma_f32_16x16x32_bf16(ah[fr], bh, acc[fr][fc], 0, 0, 0);
                acc[fr][fc] = __builtin_amdgcn_mfma_f32_16x16x32_bf16(al[fr], bh, acc[fr][fc], 0, 0, 0);
                acc[fr][fc] = __builtin_amdgcn_mfma_f32_16x16x32_bf16(ah[fr], bl, acc[fr][fc], 0, 0, 0);
            }
        }
        __syncthreads();
    }
    // ---- epilogue: write fp16 plane. D col=lane&15, row=(lane>>4)*4+reg
    #pragma unroll
    for (int fr = 0; fr < 2; ++fr) {
        #pragma unroll
        for (int fc = 0; fc < FC; ++fc) {
            int col = fc * 16 + l15;
            #pragma unroll
            for (int reg = 0; reg < 4; ++reg) {
                long row = base + w * 32 + fr * 16 + (l >> 4) * 4 + reg;
                if (row < N) Xh[row * BN + col] = (f16)acc[fr][fc][reg];
            }
        }
    }
}

// ---- aggregation from fp16 plane:
// h[i] = relu( sum_e xh[src_e]*nv_e + xh[i]*disq[i]^2 + bias ), fp32 accum.
// LPE = C/8 lanes per edge (f16x8 = 16B/lane); EPW = 64/LPE edges per wave.
template <int C, bool B16OUT>
__global__ __launch_bounds__(256) void agg_kernel(
    const f16* __restrict__ xh, const float* __restrict__ disq,
    const int* __restrict__ rp, const int2* __restrict__ esw,
    const float* __restrict__ bias, float* __restrict__ h,
    u16* __restrict__ hhi, u16* __restrict__ hlo, int N)
{
    int i = blockIdx.x * 4 + (threadIdx.x >> 6);
    if (i >= N) return;
    int lane = threadIdx.x & 63;
    int e0 = rp[i], e1 = rp[i + 1];
    constexpr int LPE = C / 8;            // lanes per edge (16 or 8)
    constexpr int EPW = 64 / LPE;         // edges per wave load (4 or 8)
    int sub = lane / LPE;
    int col = lane % LPE;                 // 8-half group within row
    const f16x8* x8 = (const f16x8*)xh;

    float a0[8], a1[8];
    #pragma unroll
    for (int j = 0; j < 8; ++j) { a0[j] = 0.f; a1[j] = 0.f; }

    int e = e0 + sub;
    for (; e + EPW < e1; e += 2 * EPW) {
        int2 p0 = esw[e];
        int2 p1 = esw[e + EPW];
        f16x8 v0 = x8[(long)p0.x * LPE + col];
        f16x8 v1 = x8[(long)p1.x * LPE + col];
        float w0 = __int_as_float(p0.y), w1 = __int_as_float(p1.y);
        #pragma unroll
        for (int j = 0; j < 8; ++j) {
            a0[j] += (float)v0[j] * w0;
            a1[j] += (float)v1[j] * w1;
        }
    }
    for (; e < e1; e += EPW) {
        int2 p0 = esw[e];
        f16x8 v0 = x8[(long)p0.x * LPE + col];
        float w0 = __int_as_float(p0.y);
        #pragma unroll
        for (int j = 0; j < 8; ++j) a0[j] += (float)v0[j] * w0;
    }
    #pragma unroll
    for (int j = 0; j < 8; ++j) a0[j] += a1[j];
    #pragma unroll
    for (int m = LPE; m < 64; m <<= 1) {
        #pragma unroll
        for (int j = 0; j < 8; ++j) a0[j] += __shfl_xor(a0[j], m, 64);
    }
    if (sub == 0) {
        float ds = disq[i];
        float ws = ds * ds;
        f16x8 v = x8[(long)i * LPE + col];
        const float* bp = bias + col * 8;
        float4 b0 = *(const float4*)bp;
        float4 b1 = *(const float4*)(bp + 4);
        float bb[8] = {b0.x, b0.y, b0.z, b0.w, b1.x, b1.y, b1.z, b1.w};
        float o[8];
        #pragma unroll
        for (int j = 0; j < 8; ++j)
            o[j] = fmaxf(a0[j] + (float)v[j] * ws + bb[j], 0.f);
        if constexpr (B16OUT) {
            u16x8 oh, ol;
            #pragma unroll
            for (int j = 0; j < 8; ++j) {
                u16 hh = bf16_rne(o[j]);
                oh[j] = hh;
                ol[j] = bf16_rne(o[j] - bf16_f(hh));
            }
            *(u16x8*)&hhi[(long)i * C + col * 8] = oh;
            *(u16x8*)&hlo[(long)i * C + col * 8] = ol;
        } else {
            float4 v0 = {o[0], o[1], o[2], o[3]};
            float4 v1 = {o[4], o[5], o[6], o[7]};
            *(float4*)&h[(long)i * C + col * 8] = v0;
            *(float4*)&h[(long)i * C + col * 8 + 4] = v1;
        }
    }
}

// ---- global max pool: batch sorted -> per-block running max, flush on change
__global__ __launch_bounds__(256) void pool_kernel(
    const float* __restrict__ h, const int* __restrict__ batch,
    float* __restrict__ g, int N)
{
    int c = threadIdx.x & 63;
    int slot = threadIdx.x >> 6;
    int base = blockIdx.x * 512;
    int end = base + 512; if (end > N) end = N;
    int cur = -1; float m = 0.f;
    for (int n = base + slot; n < end; n += 4) {
        int b = batch[n];
        float v = h[(long)n * 64 + c];
        if (b != cur) {
            if (cur >= 0) atomicMax((int*)&g[cur * 64 + c], __float_as_int(m));
            cur = b; m = v;
        } else {
            m = fmaxf(m, v);
        }
    }
    if (cur >= 0) atomicMax((int*)&g[cur * 64 + c], __float_as_int(m));
}

// ---- head: out[r] = relu(g[r]@Wh1+bh1) @ Wh2 + bh2
__global__ void head_kernel(const float* __restrict__ g, const float* __restrict__ Wh1,
                            const float* __restrict__ bh1, const float* __restrict__ Wh2,
                            const float* __restrict__ bh2, float* __restrict__ out, int G) {
    int r = threadIdx.x;
    if (r >= G) return;
    float hid[32];
    #pragma unroll
    for (int j = 0; j < 32; ++j) {
        float s = bh1[j];
        for (int k = 0; k < 64; ++k) s += g[r * 64 + k] * Wh1[k * 32 + j];
        hid[j] = fmaxf(s, 0.f);
    }
    float o = bh2[0];
    #pragma unroll
    for (int j = 0; j < 32; ++j) o += hid[j] * Wh2[j];
    out[r] = o;
}

extern "C" void kernel_launch(void* const* d_in, const int* in_sizes, int n_in,
                              void* d_out, int out_size, void* d_ws, size_t ws_size,
                              hipStream_t stream) {
    const float* x   = (const float*)d_in[0];
    const int*   ei  = (const int*)d_in[1];
    const int*   bat = (const int*)d_in[2];
    const float* W1  = (const float*)d_in[3];
    const float* b1  = (const float*)d_in[4];
    const float* W2  = (const float*)d_in[5];
    const float* b2  = (const float*)d_in[6];
    const float* W3  = (const float*)d_in[7];
    const float* b3  = (const float*)d_in[8];
    const float* Wh1 = (const float*)d_in[9];
    const float* bh1 = (const float*)d_in[10];
    const float* Wh2 = (const float*)d_in[11];
    const float* bh2 = (const float*)d_in[12];
    float* out = (float*)d_out;

    const int N = in_sizes[2];
    const int E = in_sizes[1] / 2;
    const int K1 = in_sizes[0] / N;          // 397
    const int G = out_size;                  // 64
    const int KP1 = ((K1 + 31) / 32) * 32;   // 416

    char* wsp = (char*)d_ws;
    size_t off = 0;
    auto alloc = [&](size_t bytes) -> void* {
        void* p = wsp + off;
        off = (off + bytes + 255) & ~(size_t)255;
        return p;
    };
    int*   cnt   = (int*)alloc((size_t)N * 4);
    float* disq  = (float*)alloc((size_t)N * 4);
    int*   rp    = (int*)alloc((size_t)(N + 1) * 4);
    int*   bsum  = (int*)alloc(256 * 4);
    int*   boff  = (int*)alloc(256 * 4);
    int2*  esw   = (int2*)alloc((size_t)E * 8);
    u16*   Wt1hi = (u16*)alloc((size_t)KP1 * 128 * 2);
    u16*   Wt1lo = (u16*)alloc((size_t)KP1 * 128 * 2);
    u16*   Wt2hi = (u16*)alloc((size_t)128 * 128 * 2);
    u16*   Wt2lo = (u16*)alloc((size_t)128 * 128 * 2);
    u16*   Wt3hi = (u16*)alloc((size_t)128 * 64 * 2);
    u16*   Wt3lo = (u16*)alloc((size_t)128 * 64 * 2);
    f16*   Xh    = (f16*)alloc((size_t)N * 128 * 2);     // GEMM out (fp16 plane)
    u16*   Hhi   = (u16*)alloc((size_t)N * 128 * 2);     // agg out hi
    u16*   Hlo   = (u16*)alloc((size_t)N * 128 * 2);     // agg out lo
    float* h3    = (float*)alloc((size_t)N * 64 * 4);    // layer-3 agg out
    float* g     = (float*)alloc((size_t)G * 64 * 4);

    const int nchunks = (N + 1023) / 1024;

    (void)hipMemsetAsync(cnt, 0, (size_t)N * 4, stream);
    deg_count_kernel<<<(E + 255) / 256, 256, 0, stream>>>(ei, cnt, E);
    deg_fin_kernel<<<(N + 255) / 256, 256, 0, stream>>>(cnt, disq, N);
    scan_pass1<<<nchunks, 256, 0, stream>>>(cnt, bsum, N);
    scan_pass2<<<1, 256, 0, stream>>>(bsum, boff, nchunks, rp, N, E);
    scan_pass3<<<nchunks, 256, 0, stream>>>(cnt, boff, rp, N);
    (void)hipMemsetAsync(cnt, 0, (size_t)N * 4, stream);
    scatter_kernel<<<(E + 255) / 256, 256, 0, stream>>>(ei, disq, rp, cnt, esw, E);

    // weight conversions (tiny)
    cvtw_kernel<<<(KP1 * 128 + 255) / 256, 256, 0, stream>>>(W1, Wt1hi, Wt1lo, K1, KP1, 128);
    cvtw_kernel<<<(128 * 128 + 255) / 256, 256, 0, stream>>>(W2, Wt2hi, Wt2lo, 128, 128, 128);
    cvtw_kernel<<<(128 * 64 + 255) / 256, 256, 0, stream>>>(W3, Wt3hi, Wt3lo, 128, 128, 64);

    int gblocks = (N + 127) / 128;
    int ablocks = (N + 3) / 4;
    // layer 1
    mfma_gemm<128, true><<<gblocks, 256, 0, stream>>>(x, nullptr, nullptr, Wt1hi, Wt1lo, Xh, N, K1, KP1);
    agg_kernel<128, true><<<ablocks, 256, 0, stream>>>(Xh, disq, rp, esw, b1, nullptr, Hhi, Hlo, N);
    // layer 2
    mfma_gemm<128, false><<<gblocks, 256, 0, stream>>>(nullptr, Hhi, Hlo, Wt2hi, Wt2lo, Xh, N, 128, 128);
    agg_kernel<128, true><<<ablocks, 256, 0, stream>>>(Xh, disq, rp, esw, b2, nullptr, Hhi, Hlo, N);
    // layer 3
    mfma_gemm<64, false><<<gblocks, 256, 0, stream>>>(nullptr, Hhi, Hlo, Wt3hi, Wt3lo, Xh, N, 128, 128);
    agg_kernel<64, false><<<ablocks, 256, 0, stream>>>(Xh, disq, rp, esw, b3, h3, nullptr, nullptr, N);
    // pool + head
    (void)hipMemsetAsync(g, 0, (size_t)G * 64 * 4, stream);
    pool_kernel<<<(N + 511) / 512, 256, 0, stream>>>(h3, bat, g, N);
    head_kernel<<<1, 64, 0, stream>>>(g, Wh1, bh1, Wh2, bh2, out, G);
}

// Round 14
// 531.371 us; speedup vs baseline: 1.6241x; 1.0296x over previous
//
#include <hip/hip_runtime.h>
#include <hip/hip_bf16.h>
#include <hip/hip_fp16.h>

// ---------------------------------------------------------------------------
// GCN: 3x (GEMM -> sym-normalized aggregation(+self-loop) -> +bias -> ReLU)
//      -> global max pool per graph -> MLP head.
// GEMM via MFMA bf16 hi/lo split (3 products, ~16-bit mantissa):
//   512 thr (8 waves x 16 rows), A loaded DIRECT to registers (convert
//   in-reg), only W staged in LDS (16KB) -> high occupancy, no A ds_writes.
// GEMM output written as fp16 plane; agg gathers fp16 (half bytes),
//   accumulates fp32, emits bf16 hi/lo for the next GEMM.
// ---------------------------------------------------------------------------

typedef float f4u __attribute__((ext_vector_type(4), aligned(4)));
typedef unsigned short u16;
typedef u16 u16x8 __attribute__((ext_vector_type(8)));
typedef short bf16x8 __attribute__((ext_vector_type(8)));
typedef float f32x4 __attribute__((ext_vector_type(4)));
typedef _Float16 f16;
typedef f16 f16x8 __attribute__((ext_vector_type(8)));

__device__ __forceinline__ u16 bf16_rne(float f) {
    unsigned u = __float_as_uint(f);
    return (u16)((u + 0x7FFF + ((u >> 16) & 1)) >> 16);
}
__device__ __forceinline__ float bf16_f(u16 h) {
    return __uint_as_float(((unsigned)h) << 16);
}

__global__ void deg_count_kernel(const int* __restrict__ ei, int* __restrict__ cnt, int E) {
    int e = blockIdx.x * 256 + threadIdx.x;
    if (e < E) atomicAdd(&cnt[ei[E + e]], 1);
}

__global__ void deg_fin_kernel(const int* __restrict__ cnt, float* __restrict__ disq, int N) {
    int i = blockIdx.x * 256 + threadIdx.x;
    if (i < N) disq[i] = rsqrtf((float)cnt[i] + 1.0f);
}

__global__ void scan_pass1(const int* __restrict__ cnt, int* __restrict__ bsum, int N) {
    __shared__ int s[256];
    int t = threadIdx.x;
    int base = blockIdx.x * 1024 + t * 4;
    int sum = 0;
    #pragma unroll
    for (int j = 0; j < 4; ++j) { int idx = base + j; if (idx < N) sum += cnt[idx]; }
    s[t] = sum; __syncthreads();
    for (int off = 128; off; off >>= 1) {
        if (t < off) s[t] += s[t + off];
        __syncthreads();
    }
    if (t == 0) bsum[blockIdx.x] = s[0];
}

__global__ void scan_pass2(const int* __restrict__ bsum, int* __restrict__ boff,
                           int nchunks, int* __restrict__ rp, int N, int E) {
    __shared__ int s[256];
    int t = threadIdx.x;
    int v = (t < nchunks) ? bsum[t] : 0;
    s[t] = v; __syncthreads();
    for (int off = 1; off < 256; off <<= 1) {
        int x = (t >= off) ? s[t - off] : 0;
        __syncthreads();
        s[t] += x;
        __syncthreads();
    }
    boff[t] = s[t] - v;
    if (t == 0) rp[N] = E;
}

__global__ void scan_pass3(const int* __restrict__ cnt, const int* __restrict__ boff,
                           int* __restrict__ rp, int N) {
    __shared__ int s[256];
    int t = threadIdx.x;
    int base = blockIdx.x * 1024 + t * 4;
    int v[4]; int sum = 0;
    #pragma unroll
    for (int j = 0; j < 4; ++j) { int idx = base + j; v[j] = (idx < N) ? cnt[idx] : 0; sum += v[j]; }
    s[t] = sum; __syncthreads();
    for (int off = 1; off < 256; off <<= 1) {
        int x = (t >= off) ? s[t - off] : 0;
        __syncthreads();
        s[t] += x;
        __syncthreads();
    }
    int ex = s[t] - sum + boff[blockIdx.x];
    #pragma unroll
    for (int j = 0; j < 4; ++j) { int idx = base + j; if (idx < N) { rp[idx] = ex; ex += v[j]; } }
}

__global__ void scatter_kernel(const int* __restrict__ ei, const float* __restrict__ disq,
                               const int* __restrict__ rp, int* __restrict__ fill,
                               int2* __restrict__ esw, int E) {
    int e = blockIdx.x * 256 + threadIdx.x;
    if (e >= E) return;
    int s = ei[e];
    int d = ei[E + e];
    int pos = rp[d] + atomicAdd(&fill[d], 1);
    int2 p; p.x = s; p.y = __float_as_int(disq[s] * disq[d]);
    esw[pos] = p;
}

// ---- W convert+transpose: Wt[c][k] = hi/lo(W[k][c]), k zero-padded to KP
__global__ void cvtw_kernel(const float* __restrict__ W, u16* __restrict__ Wthi,
                            u16* __restrict__ Wtlo, int K, int KP, int BN) {
    int idx = blockIdx.x * 256 + threadIdx.x;
    if (idx >= KP * BN) return;
    int c = idx / KP;
    int k = idx % KP;
    float v = (k < K) ? W[(long)k * BN + c] : 0.f;
    u16 h = bf16_rne(v);
    Wthi[idx] = h;
    Wtlo[idx] = bf16_rne(v - bf16_f(h));
}

// ---- MFMA GEMM: Xh[N,BN] fp16 = A[N,K] @ W[K,BN] via bf16 hi/lo split.
// BM=128, BK=32, 512 thr (8 waves x 16 rows x BN cols).
// A: direct global->register per lane (row=base+w*16+(l&15), k=koff..+7),
//    converted fp32->hi/lo in registers (or loaded from bf16 planes).
// W: pre-converted transposed Wt[c][kp], staged in LDS (stride 40).
template <int BN, bool AFP32>
__global__ __launch_bounds__(512) void mfma_gemm(
    const float* __restrict__ Af, const u16* __restrict__ Ahi,
    const u16* __restrict__ Alo, const u16* __restrict__ Wthi,
    const u16* __restrict__ Wtlo, f16* __restrict__ Xh, int N, int K, int KP)
{
    constexpr int FC = BN / 16;
    __shared__ u16 Wh[BN * 40];
    __shared__ u16 Wl[BN * 40];
    const int tid = threadIdx.x;
    const int w = tid >> 6;               // wave 0..7
    const int l = tid & 63;
    const int l15 = l & 15;
    const int koff = (l >> 4) * 8;
    const long base = (long)blockIdx.x * 128;
    const long arow = base + w * 16 + l15;      // this lane's A row
    const bool rowOK = (arow < N);

    f32x4 acc[FC];
    #pragma unroll
    for (int j = 0; j < FC; ++j) acc[j] = (f32x4){0.f, 0.f, 0.f, 0.f};

    for (int k0 = 0; k0 < KP; k0 += 32) {
        // ---- stage W into LDS: BN*4 chunks of 8 halves per plane
        {
            int i2 = tid;
            if (i2 < BN * 4) {
                int c = i2 >> 2;
                int kq = (i2 & 3) * 8;
                *(u16x8*)&Wh[c * 40 + kq] = *(const u16x8*)&Wthi[(long)c * KP + k0 + kq];
                *(u16x8*)&Wl[c * 40 + kq] = *(const u16x8*)&Wtlo[(long)c * KP + k0 + kq];
            }
        }
        // ---- A fragment direct to registers
        bf16x8 ah, al;
        {
            u16x8 hv = (u16x8)0, lv = (u16x8)0;
            if constexpr (AFP32) {
                int rem = K - (k0 + koff);
                if (rowOK && rem > 0) {
                    const float* ap = &Af[arow * (long)K + k0 + koff];
                    float f[8];
                    if (rem >= 8) {
                        f4u v0 = *(const f4u*)ap;
                        f4u v1 = *(const f4u*)(ap + 4);
                        f[0] = v0.x; f[1] = v0.y; f[2] = v0.z; f[3] = v0.w;
                        f[4] = v1.x; f[5] = v1.y; f[6] = v1.z; f[7] = v1.w;
                    } else {
                        #pragma unroll
                        for (int j = 0; j < 8; ++j) f[j] = (j < rem) ? ap[j] : 0.f;
                    }
                    #pragma unroll
                    for (int j = 0; j < 8; ++j) {
                        u16 h = bf16_rne(f[j]);
                        hv[j] = h;
                        lv[j] = bf16_rne(f[j] - bf16_f(h));
                    }
                }
            } else {
                if (rowOK) {
                    hv = *(const u16x8*)&Ahi[arow * (long)K + k0 + koff];
                    lv = *(const u16x8*)&Alo[arow * (long)K + k0 + koff];
                }
            }
            ah = __builtin_bit_cast(bf16x8, hv);
            al = __builtin_bit_cast(bf16x8, lv);
        }
        __syncthreads();
        #pragma unroll
        for (int fc = 0; fc < FC; ++fc) {
            int wr = (fc * 16 + l15) * 40 + koff;
            bf16x8 bh = *(const bf16x8*)&Wh[wr];
            bf16x8 bl = *(const bf16x8*)&Wl[wr];
            acc[fc] = __builtin_amdgcn_mfma_f32_16x16x32_bf16(ah, bh, acc[fc], 0, 0, 0);
            acc[fc] = __builtin_amdgcn_mfma_f32_16x16x32_bf16(al, bh, acc[fc], 0, 0, 0);
            acc[fc] = __builtin_amdgcn_mfma_f32_16x16x32_bf16(ah, bl, acc[fc], 0, 0, 0);
        }
        __syncthreads();
    }
    // ---- epilogue: write fp16 plane. D col=lane&15, row=(lane>>4)*4+reg
    #pragma unroll
    for (int fc = 0; fc < FC; ++fc) {
        int col = fc * 16 + l15;
        #pragma unroll
        for (int reg = 0; reg < 4; ++reg) {
            long row = base + w * 16 + (l >> 4) * 4 + reg;
            if (row < N) Xh[row * BN + col] = (f16)acc[fc][reg];
        }
    }
}

// ---- aggregation from fp16 plane:
// h[i] = relu( sum_e xh[src_e]*nv_e + xh[i]*disq[i]^2 + bias ), fp32 accum.
// LPE = C/8 lanes per edge (f16x8 = 16B/lane); EPW = 64/LPE edges per wave.
template <int C, bool B16OUT>
__global__ __launch_bounds__(256) void agg_kernel(
    const f16* __restrict__ xh, const float* __restrict__ disq,
    const int* __restrict__ rp, const int2* __restrict__ esw,
    const float* __restrict__ bias, float* __restrict__ h,
    u16* __restrict__ hhi, u16* __restrict__ hlo, int N)
{
    int i = blockIdx.x * 4 + (threadIdx.x >> 6);
    if (i >= N) return;
    int lane = threadIdx.x & 63;
    int e0 = rp[i], e1 = rp[i + 1];
    constexpr int LPE = C / 8;            // lanes per edge (16 or 8)
    constexpr int EPW = 64 / LPE;         // edges per wave load (4 or 8)
    int sub = lane / LPE;
    int col = lane % LPE;                 // 8-half group within row
    const f16x8* x8 = (const f16x8*)xh;

    float a0[8], a1[8];
    #pragma unroll
    for (int j = 0; j < 8; ++j) { a0[j] = 0.f; a1[j] = 0.f; }

    int e = e0 + sub;
    for (; e + EPW < e1; e += 2 * EPW) {
        int2 p0 = esw[e];
        int2 p1 = esw[e + EPW];
        f16x8 v0 = x8[(long)p0.x * LPE + col];
        f16x8 v1 = x8[(long)p1.x * LPE + col];
        float w0 = __int_as_float(p0.y), w1 = __int_as_float(p1.y);
        #pragma unroll
        for (int j = 0; j < 8; ++j) {
            a0[j] += (float)v0[j] * w0;
            a1[j] += (float)v1[j] * w1;
        }
    }
    for (; e < e1; e += EPW) {
        int2 p0 = esw[e];
        f16x8 v0 = x8[(long)p0.x * LPE + col];
        float w0 = __int_as_float(p0.y);
        #pragma unroll
        for (int j = 0; j < 8; ++j) a0[j] += (float)v0[j] * w0;
    }
    #pragma unroll
    for (int j = 0; j < 8; ++j) a0[j] += a1[j];
    #pragma unroll
    for (int m = LPE; m < 64; m <<= 1) {
        #pragma unroll
        for (int j = 0; j < 8; ++j) a0[j] += __shfl_xor(a0[j], m, 64);
    }
    if (sub == 0) {
        float ds = disq[i];
        float ws = ds * ds;
        f16x8 v = x8[(long)i * LPE + col];
        const float* bp = bias + col * 8;
        float4 b0 = *(const float4*)bp;
        float4 b1 = *(const float4*)(bp + 4);
        float bb[8] = {b0.x, b0.y, b0.z, b0.w, b1.x, b1.y, b1.z, b1.w};
        float o[8];
        #pragma unroll
        for (int j = 0; j < 8; ++j)
            o[j] = fmaxf(a0[j] + (float)v[j] * ws + bb[j], 0.f);
        if constexpr (B16OUT) {
            u16x8 oh, ol;
            #pragma unroll
            for (int j = 0; j < 8; ++j) {
                u16 hh = bf16_rne(o[j]);
                oh[j] = hh;
                ol[j] = bf16_rne(o[j] - bf16_f(hh));
            }
            *(u16x8*)&hhi[(long)i * C + col * 8] = oh;
            *(u16x8*)&hlo[(long)i * C + col * 8] = ol;
        } else {
            float4 v0 = {o[0], o[1], o[2], o[3]};
            float4 v1 = {o[4], o[5], o[6], o[7]};
            *(float4*)&h[(long)i * C + col * 8] = v0;
            *(float4*)&h[(long)i * C + col * 8 + 4] = v1;
        }
    }
}

// ---- global max pool: batch sorted -> per-block running max, flush on change
__global__ __launch_bounds__(256) void pool_kernel(
    const float* __restrict__ h, const int* __restrict__ batch,
    float* __restrict__ g, int N)
{
    int c = threadIdx.x & 63;
    int slot = threadIdx.x >> 6;
    int base = blockIdx.x * 512;
    int end = base + 512; if (end > N) end = N;
    int cur = -1; float m = 0.f;
    for (int n = base + slot; n < end; n += 4) {
        int b = batch[n];
        float v = h[(long)n * 64 + c];
        if (b != cur) {
            if (cur >= 0) atomicMax((int*)&g[cur * 64 + c], __float_as_int(m));
            cur = b; m = v;
        } else {
            m = fmaxf(m, v);
        }
    }
    if (cur >= 0) atomicMax((int*)&g[cur * 64 + c], __float_as_int(m));
}

// ---- head: out[r] = relu(g[r]@Wh1+bh1) @ Wh2 + bh2
__global__ void head_kernel(const float* __restrict__ g, const float* __restrict__ Wh1,
                            const float* __restrict__ bh1, const float* __restrict__ Wh2,
                            const float* __restrict__ bh2, float* __restrict__ out, int G) {
    int r = threadIdx.x;
    if (r >= G) return;
    float hid[32];
    #pragma unroll
    for (int j = 0; j < 32; ++j) {
        float s = bh1[j];
        for (int k = 0; k < 64; ++k) s += g[r * 64 + k] * Wh1[k * 32 + j];
        hid[j] = fmaxf(s, 0.f);
    }
    float o = bh2[0];
    #pragma unroll
    for (int j = 0; j < 32; ++j) o += hid[j] * Wh2[j];
    out[r] = o;
}

extern "C" void kernel_launch(void* const* d_in, const int* in_sizes, int n_in,
                              void* d_out, int out_size, void* d_ws, size_t ws_size,
                              hipStream_t stream) {
    const float* x   = (const float*)d_in[0];
    const int*   ei  = (const int*)d_in[1];
    const int*   bat = (const int*)d_in[2];
    const float* W1  = (const float*)d_in[3];
    const float* b1  = (const float*)d_in[4];
    const float* W2  = (const float*)d_in[5];
    const float* b2  = (const float*)d_in[6];
    const float* W3  = (const float*)d_in[7];
    const float* b3  = (const float*)d_in[8];
    const float* Wh1 = (const float*)d_in[9];
    const float* bh1 = (const float*)d_in[10];
    const float* Wh2 = (const float*)d_in[11];
    const float* bh2 = (const float*)d_in[12];
    float* out = (float*)d_out;

    const int N = in_sizes[2];
    const int E = in_sizes[1] / 2;
    const int K1 = in_sizes[0] / N;          // 397
    const int G = out_size;                  // 64
    const int KP1 = ((K1 + 31) / 32) * 32;   // 416

    char* wsp = (char*)d_ws;
    size_t off = 0;
    auto alloc = [&](size_t bytes) -> void* {
        void* p = wsp + off;
        off = (off + bytes + 255) & ~(size_t)255;
        return p;
    };
    int*   cnt   = (int*)alloc((size_t)N * 4);
    float* disq  = (float*)alloc((size_t)N * 4);
    int*   rp    = (int*)alloc((size_t)(N + 1) * 4);
    int*   bsum  = (int*)alloc(256 * 4);
    int*   boff  = (int*)alloc(256 * 4);
    int2*  esw   = (int2*)alloc((size_t)E * 8);
    u16*   Wt1hi = (u16*)alloc((size_t)KP1 * 128 * 2);
    u16*   Wt1lo = (u16*)alloc((size_t)KP1 * 128 * 2);
    u16*   Wt2hi = (u16*)alloc((size_t)128 * 128 * 2);
    u16*   Wt2lo = (u16*)alloc((size_t)128 * 128 * 2);
    u16*   Wt3hi = (u16*)alloc((size_t)128 * 64 * 2);
    u16*   Wt3lo = (u16*)alloc((size_t)128 * 64 * 2);
    f16*   Xh    = (f16*)alloc((size_t)N * 128 * 2);     // GEMM out (fp16 plane)
    u16*   Hhi   = (u16*)alloc((size_t)N * 128 * 2);     // agg out hi
    u16*   Hlo   = (u16*)alloc((size_t)N * 128 * 2);     // agg out lo
    float* h3    = (float*)alloc((size_t)N * 64 * 4);    // layer-3 agg out
    float* g     = (float*)alloc((size_t)G * 64 * 4);

    const int nchunks = (N + 1023) / 1024;

    (void)hipMemsetAsync(cnt, 0, (size_t)N * 4, stream);
    deg_count_kernel<<<(E + 255) / 256, 256, 0, stream>>>(ei, cnt, E);
    deg_fin_kernel<<<(N + 255) / 256, 256, 0, stream>>>(cnt, disq, N);
    scan_pass1<<<nchunks, 256, 0, stream>>>(cnt, bsum, N);
    scan_pass2<<<1, 256, 0, stream>>>(bsum, boff, nchunks, rp, N, E);
    scan_pass3<<<nchunks, 256, 0, stream>>>(cnt, boff, rp, N);
    (void)hipMemsetAsync(cnt, 0, (size_t)N * 4, stream);
    scatter_kernel<<<(E + 255) / 256, 256, 0, stream>>>(ei, disq, rp, cnt, esw, E);

    // weight conversions (tiny)
    cvtw_kernel<<<(KP1 * 128 + 255) / 256, 256, 0, stream>>>(W1, Wt1hi, Wt1lo, K1, KP1, 128);
    cvtw_kernel<<<(128 * 128 + 255) / 256, 256, 0, stream>>>(W2, Wt2hi, Wt2lo, 128, 128, 128);
    cvtw_kernel<<<(128 * 64 + 255) / 256, 256, 0, stream>>>(W3, Wt3hi, Wt3lo, 128, 128, 64);

    int gblocks = (N + 127) / 128;
    int ablocks = (N + 3) / 4;
    // layer 1
    mfma_gemm<128, true><<<gblocks, 512, 0, stream>>>(x, nullptr, nullptr, Wt1hi, Wt1lo, Xh, N, K1, KP1);
    agg_kernel<128, true><<<ablocks, 256, 0, stream>>>(Xh, disq, rp, esw, b1, nullptr, Hhi, Hlo, N);
    // layer 2
    mfma_gemm<128, false><<<gblocks, 512, 0, stream>>>(nullptr, Hhi, Hlo, Wt2hi, Wt2lo, Xh, N, 128, 128);
    agg_kernel<128, true><<<ablocks, 256, 0, stream>>>(Xh, disq, rp, esw, b2, nullptr, Hhi, Hlo, N);
    // layer 3
    mfma_gemm<64, false><<<gblocks, 512, 0, stream>>>(nullptr, Hhi, Hlo, Wt3hi, Wt3lo, Xh, N, 128, 128);
    agg_kernel<64, false><<<ablocks, 256, 0, stream>>>(Xh, disq, rp, esw, b3, h3, nullptr, nullptr, N);
    // pool + head
    (void)hipMemsetAsync(g, 0, (size_t)G * 64 * 4, stream);
    pool_kernel<<<(N + 511) / 512, 256, 0, stream>>>(h3, bat, g, N);
    head_kernel<<<1, 64, 0, stream>>>(g, Wh1, bh1, Wh2, bh2, out, G);
}